// Round 12
// baseline (1105.854 us; speedup 1.0000x reference)
//
#include <hip/hip_runtime.h>
#include <math.h>

typedef unsigned int u32;
typedef unsigned short u16;

#define NS 128          // T-1 timesteps
#define A_ 5
#define B_ 128
#define NTH 1024
#define BC 16
#define NWG 40          // 5 agents x 8 chunks of 16 rows
#define LOG2PI_F 1.8378770664093453f

// ---- B-fragment packed weight layout (u16 units), per agent ----
// frag order: [layer][ntile][kstep][lane 0..63][j 0..7], elem = W[k][n] with
// k = kstep*32 + (lane>>4)*8 + j, n = ntile*16 + (lane&15).   (verified R10/R11, absmax 0)
#define OF_E1 0         // 8 ntiles x 5 ksteps
#define OF_P1 20480
#define OF_D1 40960
#define OF_G  61440     // 24 ntiles x 5
#define OF_E2 122880    // 8 x 4
#define OF_P2 139264
#define OF_D2 155648
#define OF_H  172032    // 4 heads x (1 x 4)
#define OF_DH 180224    // 1 x 4 (cols: dm0 dm1 ds0 ds1, rest 0)
#define AGE   182272

typedef _Float16 f16x8 __attribute__((ext_vector_type(8)));
typedef float f32x4 __attribute__((ext_vector_type(4)));

__device__ __forceinline__ u16 f2h(float f) { _Float16 h = (_Float16)f; return __builtin_bit_cast(u16, h); }
__device__ __forceinline__ float h2f(u16 u) { return (float)__builtin_bit_cast(_Float16, u); }
__device__ __forceinline__ float softplusf_(float x) { return fmaxf(x, 0.f) + log1pf(expf(-fabsf(x))); }
__device__ __forceinline__ float sigmoidf_(float x) { return 1.f / (1.f + expf(-x)); }

#define MFMA16(af, bf, acc) __builtin_amdgcn_mfma_f32_16x16x32_f16((af), (bf), (acc), 0, 0, 0)

#define UST 168   // Uf row stride (elems)
#define AST 136   // activation row stride

struct PM {
    const float* __restrict__ y;
    const float* __restrict__ eps;
    const float* __restrict__ eb1; const float* __restrict__ eb2;
    const float* __restrict__ pb1; const float* __restrict__ pb2;
    const float* __restrict__ db1; const float* __restrict__ db2;
    const float* __restrict__ emb; const float* __restrict__ esb;
    const float* __restrict__ pmb; const float* __restrict__ psb;
    const float* __restrict__ dmb; const float* __restrict__ dsb;
    const float* __restrict__ bih; const float* __restrict__ bhh;
    const u16* __restrict__ wq;
    float* __restrict__ partials;
};

// 16 waves = 4 waves/SIMD (64-VGPR cap). MFMA working set is small enough
// to fit (1 acc + 1-2 frags), unlike the fdot2 designs that spilled (R5/R8).
// Every GEMM phase is 16-tile wave-parallel; GRU gate math pipelined P6a/P6b.
__global__ void __launch_bounds__(NTH, 1) vrnn12(PM p) {
    const int tid = threadIdx.x;
    const int wave = tid >> 6;               // 0..15
    const int lane = tid & 63;
    const int ln = lane & 15;                // fragment row/col index
    const int lq = lane >> 4;                // k-quad / row-quad
    const int a = blockIdx.x >> 3;
    const int b0 = (blockIdx.x & 7) * BC;
    const int wh = wave & 7;                 // column tile group
    const bool hiw = (wave >= 8);

    __shared__ __align__(16) u16 GL[61440];          // GRU B-frags, 120KB
    __shared__ __align__(16) u16 Uf[16 * UST];       // [x2 y10 z16 pad4 h128]
    __shared__ __align__(16) u16 aAf[16 * AST], aBf[16 * AST], aCf[16 * AST], aDf[16 * AST];
    __shared__ float mueL[16][17], sdeL[16][17], mupL[16][17], sdpL[16][17];
    __shared__ float xf[16][2], dmuL[16][2], dsdL[16][2];
    __shared__ float bE1L[128], bP1L[128], bD1L[128];
    __shared__ float bE2L[128], bP2L[128], bD2L[128];
    __shared__ float bIHL[384], bHHL[384], bHl[64], bDHl[4];
    __shared__ float redW[32];

    const f16x8* __restrict__ W8 = (const f16x8*)p.wq + (size_t)a * (AGE / 8);

    // ---- init: copy G to LDS, biases, zero U ----
    {
        const uint4* gsrc = (const uint4*)(p.wq + (size_t)a * AGE + OF_G);
        uint4* gdst = (uint4*)GL;
        for (int i = tid; i < 61440 / 8; i += NTH) gdst[i] = gsrc[i];
    }
    for (int i = tid; i < 16 * UST; i += NTH) Uf[i] = 0;
    if (tid < 128) {
        bE1L[tid] = p.eb1[a * 128 + tid]; bE2L[tid] = p.eb2[a * 128 + tid];
        bP1L[tid] = p.pb1[a * 128 + tid]; bP2L[tid] = p.pb2[a * 128 + tid];
        bD1L[tid] = p.db1[a * 128 + tid]; bD2L[tid] = p.db2[a * 128 + tid];
    }
    if (tid < 384) { bIHL[tid] = p.bih[a * 384 + tid]; bHHL[tid] = p.bhh[a * 384 + tid]; }
    if (tid < 64) {
        int h = tid >> 4, c = tid & 15;
        bHl[tid] = ((h == 0) ? p.emb : (h == 1) ? p.esb : (h == 2) ? p.pmb : p.psb)[a * 16 + c];
    }
    if (tid < 4) bDHl[tid] = (tid < 2) ? p.dmb[a * 2 + tid] : p.dsb[a * 2 + (tid - 2)];

    // ---- prefetch t=0 inputs ----
    const int ry = tid / 10, jy = tid - ry * 10;            // tid<160
    const int rx = (tid - 160) >> 1, xdx = (tid - 160) & 1; // 160<=tid<192
    const int re = tid >> 4, ze = tid & 15;                 // tid<256
    float ypre = 0.f, xpre = 0.f, epre = 0.f;
    if (tid < 160) ypre = p.y[0 * (B_ * 10) + (b0 + ry) * 10 + jy];
    else if (tid < 192) xpre = p.y[1 * (B_ * 10) + (b0 + rx) * 10 + a * 2 + xdx];
    if (tid < 256) epre = p.eps[(((size_t)0 * A_ + a) * B_ + (b0 + re)) * 16 + ze];

    float kl_acc = 0.f, nll_acc = 0.f;

#pragma unroll 1
    for (int t = 0; t < NS; ++t) {
        const int tn = (t + 1 < NS) ? t + 1 : t;
        __syncthreads();
        // ---- P1: commit inputs, prefetch next ----
        if (tid < 160) {
            Uf[ry * UST + 2 + jy] = f2h(ypre);
            ypre = p.y[tn * (B_ * 10) + (b0 + ry) * 10 + jy];
        } else if (tid < 192) {
            Uf[rx * UST + xdx] = f2h(xpre); xf[rx][xdx] = xpre;
            xpre = p.y[(tn + 1) * (B_ * 10) + (b0 + rx) * 10 + a * 2 + xdx];
        }
        __syncthreads();

        // ---- P2: enc1 (waves 0-7 -> aAf) / pri1 (waves 8-15 -> aCf) ----
        {
            f32x4 acc = {0,0,0,0};
            const int ofs = hiw ? OF_P1 / 8 : OF_E1 / 8;
#pragma unroll
            for (int k = 0; k < 5; ++k) {
                f16x8 af = *(const f16x8*)(Uf + ln * UST + k * 32 + lq * 8);
                f16x8 bf = W8[ofs + (wh * 5 + k) * 64 + lane];
                acc = MFMA16(af, bf, acc);
            }
            int c = wh * 16 + ln;
            float bb = hiw ? bP1L[c] : bE1L[c];
            u16* dst = hiw ? aCf : aAf;
#pragma unroll
            for (int j = 0; j < 4; ++j)
                dst[(lq * 4 + j) * AST + c] = f2h(fmaxf(acc[j] + bb, 0.f));
        }
        __syncthreads();

        // ---- P3: enc2 (aAf->aBf, waves 0-7) / pri2 (aCf->aDf, waves 8-15) ----
        {
            f32x4 acc = {0,0,0,0};
            const u16* src = hiw ? aCf : aAf;
            const int ofs = hiw ? OF_P2 / 8 : OF_E2 / 8;
#pragma unroll
            for (int k = 0; k < 4; ++k) {
                f16x8 af = *(const f16x8*)(src + ln * AST + k * 32 + lq * 8);
                f16x8 bf = W8[ofs + (wh * 4 + k) * 64 + lane];
                acc = MFMA16(af, bf, acc);
            }
            int c = wh * 16 + ln;
            float bb = hiw ? bP2L[c] : bE2L[c];
            u16* dst = hiw ? aDf : aBf;
#pragma unroll
            for (int j = 0; j < 4; ++j)
                dst[(lq * 4 + j) * AST + c] = f2h(fmaxf(acc[j] + bb, 0.f));
        }
        __syncthreads();

        // ---- P4: 4 gaussian heads (waves 0-3) ----
        if (wave < 4) {
            const u16* src = (wave < 2) ? aBf : aDf;
            f32x4 acc = {0,0,0,0};
#pragma unroll
            for (int k = 0; k < 4; ++k) {
                f16x8 af = *(const f16x8*)(src + ln * AST + k * 32 + lq * 8);
                f16x8 bf = W8[OF_H / 8 + wave * 256 + k * 64 + lane];
                acc = MFMA16(af, bf, acc);
            }
            float bb = bHl[wave * 16 + ln];
#pragma unroll
            for (int j = 0; j < 4; ++j) {
                int row = lq * 4 + j;
                float v = acc[j] + bb;
                if (wave == 0)      mueL[row][ln] = v;
                else if (wave == 1) sdeL[row][ln] = softplusf_(v);
                else if (wave == 2) mupL[row][ln] = v;
                else                sdpL[row][ln] = softplusf_(v);
            }
        }
        __syncthreads();

        // ---- P5: z sample + KL (256 threads) ----
        if (tid < 256) {
            float em = mueL[re][ze], es = sdeL[re][ze], pm = mupL[re][ze], ps = sdpL[re][ze];
            float zv = fmaf(epre, es, em);
            Uf[re * UST + 12 + ze] = f2h(zv);
            float dm = em - pm;
            kl_acc += 0.5f * (2.f * (logf(ps) - logf(es)) + (es * es + dm * dm) / (ps * ps) - 1.f);
            epre = p.eps[(((size_t)tn * A_ + a) * B_ + (b0 + re)) * 16 + ze];
        }
        __syncthreads();

        // ---- P6a: low waves: dec1(L2) + gate2 (LDS, i/h split, held in regs)
        //          high waves: gate0+gate1 (LDS) -> sigmoid -> stash in aBf/aDf ----
        f32x4 g2i = {0,0,0,0}, g2h = {0,0,0,0};
        {
            int c = wh * 16 + ln;
            if (!hiw) {
                f32x4 aO = {0,0,0,0};
#pragma unroll
                for (int k = 0; k < 5; ++k) {
                    f16x8 af = *(const f16x8*)(Uf + ln * UST + k * 32 + lq * 8);
                    f16x8 bD = W8[OF_D1 / 8 + (wh * 5 + k) * 64 + lane];
                    aO = MFMA16(af, bD, aO);
                    f16x8 b2 = *(const f16x8*)(GL + ((16 + wh) * 5 + k) * 512 + lane * 8);
                    if (k == 0) g2i = MFMA16(af, b2, g2i);
                    else        g2h = MFMA16(af, b2, g2h);
                }
                float bD = bD1L[c];
#pragma unroll
                for (int j = 0; j < 4; ++j)
                    aAf[(lq * 4 + j) * AST + c] = f2h(fmaxf(aO[j] + bD, 0.f));
            } else {
                f32x4 g0 = {0,0,0,0}, g1 = {0,0,0,0};
#pragma unroll
                for (int k = 0; k < 5; ++k) {
                    f16x8 af = *(const f16x8*)(Uf + ln * UST + k * 32 + lq * 8);
                    f16x8 b0 = *(const f16x8*)(GL + ((0 + wh) * 5 + k) * 512 + lane * 8);
                    g0 = MFMA16(af, b0, g0);
                    f16x8 b1 = *(const f16x8*)(GL + ((8 + wh) * 5 + k) * 512 + lane * 8);
                    g1 = MFMA16(af, b1, g1);
                }
                float br = bIHL[c] + bHHL[c];
                float bz = bIHL[128 + c] + bHHL[128 + c];
#pragma unroll
                for (int j = 0; j < 4; ++j) {
                    int row = lq * 4 + j;
                    aBf[row * AST + c] = f2h(sigmoidf_(g0[j] + br));   // r gate
                    aDf[row * AST + c] = f2h(sigmoidf_(g1[j] + bz));   // z gate
                }
            }
        }
        __syncthreads();

        // ---- P6b: low waves combine gates, update h in Uf ----
        if (!hiw) {
            int c = wh * 16 + ln;
            float bgi = bIHL[256 + c], bgh = bHHL[256 + c];
#pragma unroll
            for (int j = 0; j < 4; ++j) {
                int row = lq * 4 + j;
                float rr = h2f(aBf[row * AST + c]);
                float zz = h2f(aDf[row * AST + c]);
                float nn = tanhf(fmaf(rr, g2h[j] + bgh, g2i[j] + bgi));
                float hold = h2f(Uf[row * UST + 32 + c]);
                Uf[row * UST + 32 + c] = f2h(fmaf(zz, hold - nn, nn));
            }
        }
        __syncthreads();

        // ---- P7: dec2 (aAf -> aBf), waves 0-7 ----
        if (!hiw) {
            f32x4 acc = {0,0,0,0};
#pragma unroll
            for (int k = 0; k < 4; ++k) {
                f16x8 af = *(const f16x8*)(aAf + ln * AST + k * 32 + lq * 8);
                f16x8 bf = W8[OF_D2 / 8 + (wh * 4 + k) * 64 + lane];
                acc = MFMA16(af, bf, acc);
            }
            int c = wh * 16 + ln;
            float bE = bD2L[c];
#pragma unroll
            for (int j = 0; j < 4; ++j)
                aBf[(lq * 4 + j) * AST + c] = f2h(fmaxf(acc[j] + bE, 0.f));
        }
        __syncthreads();

        // ---- P8: dec heads (wave 0): [16x128]x[128x4] ----
        if (wave == 0) {
            f32x4 acc = {0,0,0,0};
#pragma unroll
            for (int k = 0; k < 4; ++k) {
                f16x8 af = *(const f16x8*)(aBf + ln * AST + k * 32 + lq * 8);
                f16x8 bf = W8[OF_DH / 8 + k * 64 + lane];
                acc = MFMA16(af, bf, acc);
            }
            if (ln < 4) {
                float bb = bDHl[ln];
#pragma unroll
                for (int j = 0; j < 4; ++j) {
                    int row = lq * 4 + j;
                    float v = acc[j] + bb;
                    if (ln < 2) dmuL[row][ln] = v;
                    else        dsdL[row][ln - 2] = softplusf_(v);
                }
            }
        }
        __syncthreads();

        // ---- P9: NLL (16 rows x 2 dims) ----
        if (tid < 32) {
            int r = tid >> 1, xd = tid & 1;
            float d = xf[r][xd] - dmuL[r][xd];
            float sd = dsdL[r][xd];
            nll_acc += 0.5f * (d * d / (sd * sd) + 2.f * logf(sd) + LOG2PI_F);
        }
    }

    // ---- block reduction ----
    __syncthreads();
    {
        float k = kl_acc, n = nll_acc;
        k += __shfl_xor(k, 1);  n += __shfl_xor(n, 1);
        k += __shfl_xor(k, 2);  n += __shfl_xor(n, 2);
        k += __shfl_xor(k, 4);  n += __shfl_xor(n, 4);
        k += __shfl_xor(k, 8);  n += __shfl_xor(n, 8);
        k += __shfl_xor(k, 16); n += __shfl_xor(n, 16);
        k += __shfl_xor(k, 32); n += __shfl_xor(n, 32);
        if (lane == 0) { redW[wave] = k; redW[16 + wave] = n; }
    }
    __syncthreads();
    if (tid == 0) {
        float s = 0.f, s2 = 0.f;
#pragma unroll
        for (int i = 0; i < 16; ++i) { s += redW[i]; s2 += redW[16 + i]; }
        p.partials[blockIdx.x] = s;
        p.partials[NWG + blockIdx.x] = s2;
    }
}

// ---------------- prep: pack weights into B-fragment order ----------------
struct PrepP {
    const float* eW1; const float* pW1; const float* dW1;
    const float* wih; const float* whh;
    const float* eW2; const float* pW2; const float* dW2;
    const float* hW[4];
    const float* dmW; const float* dsW;
    u16* dst;
};

__global__ void prep4(PrepP pp) {
    const int jNT[12]  = {8,8,8,24, 8,8,8, 1,1,1,1, 1};
    const int jKST[12] = {5,5,5,5, 4,4,4, 4,4,4,4, 4};
    const int jOFS[12] = {OF_E1,OF_P1,OF_D1,OF_G, OF_E2,OF_P2,OF_D2,
                          OF_H,OF_H+2048,OF_H+4096,OF_H+6144, OF_DH};
    const int jkt[3]   = {140,138,154};

    int job = blockIdx.y;
    int nt = jNT[job], kst = jKST[job];
    int per_agent = nt * kst * 512;
    int total = A_ * per_agent;
    int idx = blockIdx.x * 256 + threadIdx.x;
    if (idx >= total) return;
    int a = idx / per_agent;
    int rem = idx - a * per_agent;
    int slot = rem >> 9;            // /512
    int within = rem & 511;
    int lane = within >> 3, j = within & 7;
    int ntile = slot / kst, kstep = slot - ntile * kst;
    int k = kstep * 32 + (lane >> 4) * 8 + j;
    int n = ntile * 16 + (lane & 15);

    float val = 0.f;
    if (job < 3) {
        int sk = -1;
        if (job == 0)      sk = (k < 12) ? k : (k >= 32 ? k - 20 : -1);
        else if (job == 1) sk = (k >= 2 && k < 12) ? k - 2 : (k >= 32 ? k - 22 : -1);
        else               sk = (k >= 2 && k < 28) ? k - 2 : (k >= 32 ? k - 6 : -1);
        const float* s = (job == 0) ? pp.eW1 : (job == 1) ? pp.pW1 : pp.dW1;
        if (sk >= 0) val = s[((size_t)a * jkt[job] + sk) * 128 + n];
    } else if (job == 3) {
        if (k < 2)                  val = pp.wih[((size_t)a * 384 + n) * 18 + k];
        else if (k >= 12 && k < 28) val = pp.wih[((size_t)a * 384 + n) * 18 + (k - 10)];
        else if (k >= 32)           val = pp.whh[((size_t)a * 384 + n) * 128 + (k - 32)];
    } else if (job < 7) {
        const float* s = (job == 4) ? pp.eW2 : (job == 5) ? pp.pW2 : pp.dW2;
        val = s[((size_t)a * 128 + k) * 128 + n];
    } else if (job < 11) {
        val = pp.hW[job - 7][((size_t)a * 128 + k) * 16 + n];
    } else {
        if (n < 2)      val = pp.dmW[((size_t)a * 128 + k) * 2 + n];
        else if (n < 4) val = pp.dsW[((size_t)a * 128 + k) * 2 + (n - 2)];
    }
    pp.dst[(size_t)a * AGE + jOFS[job] + rem] = f2h(val);
}

__global__ void finish_kernel(const float* __restrict__ partials, float* __restrict__ out) {
    int tid = threadIdx.x;   // 64 threads
    float k = (tid < NWG) ? partials[tid] : 0.f;
    float n = (tid < NWG) ? partials[NWG + tid] : 0.f;
    k += __shfl_xor(k, 1);  n += __shfl_xor(n, 1);
    k += __shfl_xor(k, 2);  n += __shfl_xor(n, 2);
    k += __shfl_xor(k, 4);  n += __shfl_xor(n, 4);
    k += __shfl_xor(k, 8);  n += __shfl_xor(n, 8);
    k += __shfl_xor(k, 16); n += __shfl_xor(n, 16);
    k += __shfl_xor(k, 32); n += __shfl_xor(n, 32);
    if (tid == 0) { out[0] = k; out[1] = n; }
}

extern "C" void kernel_launch(void* const* d_in, const int* in_sizes, int n_in,
                              void* d_out, int out_size, void* d_ws, size_t ws_size,
                              hipStream_t stream) {
    float* partials = (float*)d_ws;                 // 80 floats
    u16* wq = (u16*)((char*)d_ws + 4096);           // packed frags, ~1.78 MB

    PrepP pp;
    pp.eW1 = (const float*)d_in[2];
    pp.pW1 = (const float*)d_in[10];
    pp.dW1 = (const float*)d_in[18];
    pp.wih = (const float*)d_in[26];
    pp.whh = (const float*)d_in[27];
    pp.eW2 = (const float*)d_in[4];
    pp.pW2 = (const float*)d_in[12];
    pp.dW2 = (const float*)d_in[20];
    pp.hW[0] = (const float*)d_in[6];   // emW
    pp.hW[1] = (const float*)d_in[8];   // esW
    pp.hW[2] = (const float*)d_in[14];  // pmW
    pp.hW[3] = (const float*)d_in[16];  // psW
    pp.dmW = (const float*)d_in[22];
    pp.dsW = (const float*)d_in[24];
    pp.dst = wq;
    prep4<<<dim3(1200, 12), 256, 0, stream>>>(pp);

    PM p;
    p.y   = (const float*)d_in[0];
    p.eps = (const float*)d_in[1];
    p.eb1 = (const float*)d_in[3];  p.eb2 = (const float*)d_in[5];
    p.emb = (const float*)d_in[7];  p.esb = (const float*)d_in[9];
    p.pb1 = (const float*)d_in[11]; p.pb2 = (const float*)d_in[13];
    p.pmb = (const float*)d_in[15]; p.psb = (const float*)d_in[17];
    p.db1 = (const float*)d_in[19]; p.db2 = (const float*)d_in[21];
    p.dmb = (const float*)d_in[23]; p.dsb = (const float*)d_in[25];
    p.bih = (const float*)d_in[28]; p.bhh = (const float*)d_in[29];
    p.wq = wq;
    p.partials = partials;

    vrnn12<<<NWG, NTH, 0, stream>>>(p);
    finish_kernel<<<1, 64, 0, stream>>>(partials, (float*)d_out);
}

// Round 13
// 845.384 us; speedup vs baseline: 1.3081x; 1.3081x over previous
//
#include <hip/hip_runtime.h>
#include <math.h>

typedef unsigned int u32;
typedef unsigned short u16;

#define NS 128          // T-1 timesteps
#define A_ 5
#define B_ 128
#define NTH 512
#define BC 16
#define NWG 40          // 5 agents x 8 chunks of 16 rows
#define LOG2PI_F 1.8378770664093453f

// ---- B-fragment packed weight layout (u16 units), per agent ----
// frag order: [layer][ntile][kstep][lane 0..63][j 0..7], elem = W[k][n] with
// k = kstep*32 + (lane>>4)*8 + j, n = ntile*16 + (lane&15).   (verified R10/R11, absmax 0)
#define OF_E1 0         // 8 ntiles x 5 ksteps
#define OF_P1 20480
#define OF_D1 40960
#define OF_G  61440     // 24 ntiles x 5
#define OF_E2 122880    // 8 x 4
#define OF_P2 139264
#define OF_D2 155648
#define OF_H  172032    // 4 heads x (1 x 4)
#define OF_DH 180224    // 1 x 4 (cols: dm0 dm1 ds0 ds1, rest 0)
#define AGE   182272

typedef _Float16 f16x8 __attribute__((ext_vector_type(8)));
typedef float f32x4 __attribute__((ext_vector_type(4)));

__device__ __forceinline__ u16 f2h(float f) { _Float16 h = (_Float16)f; return __builtin_bit_cast(u16, h); }
__device__ __forceinline__ float h2f(u16 u) { return (float)__builtin_bit_cast(_Float16, u); }
__device__ __forceinline__ float softplusf_(float x) { return fmaxf(x, 0.f) + log1pf(expf(-fabsf(x))); }
__device__ __forceinline__ float sigmoidf_(float x) { return 1.f / (1.f + expf(-x)); }

#define MFMA16(af, bf, acc) __builtin_amdgcn_mfma_f32_16x16x32_f16((af), (bf), (acc), 0, 0, 0)
#define PINF8(v) asm volatile("" : "+v"(v))

#define UST 168   // Uf row stride (elems)
#define AST 136   // activation row stride

struct PM {
    const float* __restrict__ y;
    const float* __restrict__ eps;
    const float* __restrict__ eb1; const float* __restrict__ eb2;
    const float* __restrict__ pb1; const float* __restrict__ pb2;
    const float* __restrict__ db1; const float* __restrict__ db2;
    const float* __restrict__ emb; const float* __restrict__ esb;
    const float* __restrict__ pmb; const float* __restrict__ psb;
    const float* __restrict__ dmb; const float* __restrict__ dsb;
    const float* __restrict__ bih; const float* __restrict__ bhh;
    const u16* __restrict__ wq;
    float* __restrict__ partials;
};

// R11 base (512 thr, 2 waves/SIMD) + pinned E1/D1/D2 B-frags (56 VGPR, fits
// under the 128 cap) + P8/P9 fused into P1 phase -> 7 barriers/step.
__global__ void __launch_bounds__(NTH, 1) vrnn13(PM p) {
    const int tid = threadIdx.x;
    const int wave = tid >> 6;               // 0..7 = output tile group tg
    const int lane = tid & 63;
    const int ln = lane & 15;
    const int lq = lane >> 4;
    const int a = blockIdx.x >> 3;
    const int b0 = (blockIdx.x & 7) * BC;
    const int tg = wave;

    __shared__ __align__(16) u16 GL[61440];          // GRU B-frags, 120KB
    __shared__ __align__(16) u16 Uf[16 * UST];       // [x2 y10 z16 pad4 h128]
    __shared__ __align__(16) u16 aAf[16 * AST], aBf[16 * AST], aCf[16 * AST], aDf[16 * AST];
    __shared__ float mueL[16][17], sdeL[16][17], mupL[16][17], sdpL[16][17];
    __shared__ float xf2[2][16][2];                  // t-parity double buffer
    __shared__ float dmuL[16][2], dsdL[16][2];
    __shared__ float bE1L[128], bP1L[128], bD1L[128];
    __shared__ float bE2L[128], bP2L[128], bD2L[128];
    __shared__ float bIHL[384], bHHL[384], bHl[64], bDHl[4];
    __shared__ float redW[32];

    const f16x8* __restrict__ W8 = (const f16x8*)p.wq + (size_t)a * (AGE / 8);

    // ---- init: G to LDS, biases, zero U ----
    {
        const uint4* gsrc = (const uint4*)(p.wq + (size_t)a * AGE + OF_G);
        uint4* gdst = (uint4*)GL;
        for (int i = tid; i < 61440 / 8; i += NTH) gdst[i] = gsrc[i];
    }
    for (int i = tid; i < 16 * UST; i += NTH) Uf[i] = 0;
    if (tid < 128) {
        bE1L[tid] = p.eb1[a * 128 + tid]; bE2L[tid] = p.eb2[a * 128 + tid];
        bP1L[tid] = p.pb1[a * 128 + tid]; bP2L[tid] = p.pb2[a * 128 + tid];
        bD1L[tid] = p.db1[a * 128 + tid]; bD2L[tid] = p.db2[a * 128 + tid];
    }
    if (tid < 384) { bIHL[tid] = p.bih[a * 384 + tid]; bHHL[tid] = p.bhh[a * 384 + tid]; }
    if (tid < 64) {
        int h = tid >> 4, c = tid & 15;
        bHl[tid] = ((h == 0) ? p.emb : (h == 1) ? p.esb : (h == 2) ? p.pmb : p.psb)[a * 16 + c];
    }
    if (tid < 4) bDHl[tid] = (tid < 2) ? p.dmb[a * 2 + tid] : p.dsb[a * 2 + (tid - 2)];

    // ---- pinned t-invariant B-fragments: E1 (P2), D1 (P6), D2 (P7) ----
    f16x8 wE1r[5], wD1r[5], wD2r[4];
#pragma unroll
    for (int k = 0; k < 5; ++k) {
        wE1r[k] = W8[OF_E1 / 8 + (tg * 5 + k) * 64 + lane];
        wD1r[k] = W8[OF_D1 / 8 + (tg * 5 + k) * 64 + lane];
    }
#pragma unroll
    for (int k = 0; k < 4; ++k)
        wD2r[k] = W8[OF_D2 / 8 + (tg * 4 + k) * 64 + lane];
#pragma unroll
    for (int k = 0; k < 5; ++k) { PINF8(wE1r[k]); PINF8(wD1r[k]); }
#pragma unroll
    for (int k = 0; k < 4; ++k) { PINF8(wD2r[k]); }

    // ---- loader roles: waves 4-6 (tid 256..447) ----
    const int tl = tid - 256;
    const int ry = (tl >= 0) ? tl / 10 : 0, jy = (tl >= 0) ? tl - (tl / 10) * 10 : 0;   // tl<160
    const int rx = (tl - 160) >> 1, xdx = (tl - 160) & 1;                                // 160<=tl<192
    const int re = tid >> 4, ze = tid & 15;                                              // tid<256 (P5)

    // ---- prefetch t=0 inputs ----
    float ypre = 0.f, xpre = 0.f, epre = 0.f;
    if (tl >= 0 && tl < 160) ypre = p.y[0 * (B_ * 10) + (b0 + ry) * 10 + jy];
    else if (tl >= 160 && tl < 192) xpre = p.y[1 * (B_ * 10) + (b0 + rx) * 10 + a * 2 + xdx];
    if (tid < 256) epre = p.eps[(((size_t)0 * A_ + a) * B_ + (b0 + re)) * 16 + ze];

    float kl_acc = 0.f, nll_acc = 0.f;

    __syncthreads();   // GL/bias init + pins done before first use

#pragma unroll 1
    for (int t = 0; t < NS; ++t) {
        const int tn = (t + 1 < NS) ? t + 1 : t;
        // ---- P1 phase: loaders commit y/x; wave 0 does dec-heads+NLL for t-1 ----
        if (tl >= 0 && tl < 160) {
            Uf[ry * UST + 2 + jy] = f2h(ypre);
            ypre = p.y[tn * (B_ * 10) + (b0 + ry) * 10 + jy];
        } else if (tl >= 160 && tl < 192) {
            Uf[rx * UST + xdx] = f2h(xpre);
            xf2[t & 1][rx][xdx] = xpre;
            xpre = p.y[(tn + 1) * (B_ * 10) + (b0 + rx) * 10 + a * 2 + xdx];
        }
        if (wave == 0 && t > 0) {
            f32x4 acc = {0, 0, 0, 0};
#pragma unroll
            for (int k = 0; k < 4; ++k) {
                f16x8 af = *(const f16x8*)(aBf + ln * AST + k * 32 + lq * 8);
                f16x8 bf = W8[OF_DH / 8 + k * 64 + lane];
                acc = MFMA16(af, bf, acc);
            }
            if (ln < 4) {
                float bb = bDHl[ln];
#pragma unroll
                for (int j = 0; j < 4; ++j) {
                    int row = lq * 4 + j;
                    float v = acc[j] + bb;
                    if (ln < 2) dmuL[row][ln] = v;
                    else        dsdL[row][ln - 2] = softplusf_(v);
                }
            }
            asm volatile("s_waitcnt lgkmcnt(0)" ::: "memory");  // same-wave LDS RAW
            if (lane < 32) {
                int r = lane >> 1, xd = lane & 1;
                float d = xf2[(t - 1) & 1][r][xd] - dmuL[r][xd];
                float sd = dsdL[r][xd];
                nll_acc += 0.5f * (d * d / (sd * sd) + 2.f * logf(sd) + LOG2PI_F);
            }
        }
        __syncthreads();

        // ---- P2: enc1 (pinned E1) + pri1 (streamed) ----
        {
            f16x8 bp[5];
#pragma unroll
            for (int k = 0; k < 5; ++k)
                bp[k] = W8[OF_P1 / 8 + (tg * 5 + k) * 64 + lane];
            f32x4 accE = {0,0,0,0}, accP = {0,0,0,0};
#pragma unroll
            for (int k = 0; k < 5; ++k) {
                f16x8 af = *(const f16x8*)(Uf + ln * UST + k * 32 + lq * 8);
                accE = MFMA16(af, wE1r[k], accE);
                accP = MFMA16(af, bp[k], accP);
            }
            int c = tg * 16 + ln;
            float bE = bE1L[c], bP = bP1L[c];
#pragma unroll
            for (int j = 0; j < 4; ++j) {
                int row = lq * 4 + j;
                aAf[row * AST + c] = f2h(fmaxf(accE[j] + bE, 0.f));
                aCf[row * AST + c] = f2h(fmaxf(accP[j] + bP, 0.f));
            }
        }
        __syncthreads();

        // ---- P3: enc2 + pri2 (both streamed from L2) ----
        {
            f16x8 be[4], bpp[4];
#pragma unroll
            for (int k = 0; k < 4; ++k) {
                be[k]  = W8[OF_E2 / 8 + (tg * 4 + k) * 64 + lane];
                bpp[k] = W8[OF_P2 / 8 + (tg * 4 + k) * 64 + lane];
            }
            f32x4 accE = {0,0,0,0}, accP = {0,0,0,0};
#pragma unroll
            for (int k = 0; k < 4; ++k) {
                f16x8 a1 = *(const f16x8*)(aAf + ln * AST + k * 32 + lq * 8);
                f16x8 a2 = *(const f16x8*)(aCf + ln * AST + k * 32 + lq * 8);
                accE = MFMA16(a1, be[k], accE);
                accP = MFMA16(a2, bpp[k], accP);
            }
            int c = tg * 16 + ln;
            float bE = bE2L[c], bP = bP2L[c];
#pragma unroll
            for (int j = 0; j < 4; ++j) {
                int row = lq * 4 + j;
                aBf[row * AST + c] = f2h(fmaxf(accE[j] + bE, 0.f));
                aDf[row * AST + c] = f2h(fmaxf(accP[j] + bP, 0.f));
            }
        }
        __syncthreads();

        // ---- P4: 4 gaussian heads (waves 0-3; B from L2) ----
        if (wave < 4) {
            const u16* src = (wave < 2) ? aBf : aDf;
            f32x4 acc = {0,0,0,0};
#pragma unroll
            for (int k = 0; k < 4; ++k) {
                f16x8 af = *(const f16x8*)(src + ln * AST + k * 32 + lq * 8);
                f16x8 bf = W8[OF_H / 8 + wave * 256 + k * 64 + lane];
                acc = MFMA16(af, bf, acc);
            }
            float bb = bHl[wave * 16 + ln];
#pragma unroll
            for (int j = 0; j < 4; ++j) {
                int row = lq * 4 + j;
                float v = acc[j] + bb;
                if (wave == 0)      mueL[row][ln] = v;
                else if (wave == 1) sdeL[row][ln] = softplusf_(v);
                else if (wave == 2) mupL[row][ln] = v;
                else                sdpL[row][ln] = softplusf_(v);
            }
        }
        __syncthreads();

        // ---- P5: z sample + KL (256 threads) ----
        if (tid < 256) {
            float em = mueL[re][ze], es = sdeL[re][ze], pm = mupL[re][ze], ps = sdpL[re][ze];
            float zv = fmaf(epre, es, em);
            Uf[re * UST + 12 + ze] = f2h(zv);
            float dm = em - pm;
            kl_acc += 0.5f * (2.f * (logf(ps) - logf(es)) + (es * es + dm * dm) / (ps * ps) - 1.f);
            epre = p.eps[(((size_t)tn * A_ + a) * B_ + (b0 + re)) * 16 + ze];
        }
        __syncthreads();

        // ---- P6: dec1 (pinned D1) + GRU gates (GL LDS) ----
        float hn[4];
        {
            f32x4 aO = {0,0,0,0}, g0 = {0,0,0,0}, g1 = {0,0,0,0};
            f32x4 g2i = {0,0,0,0}, g2h = {0,0,0,0};
#pragma unroll
            for (int k = 0; k < 5; ++k) {
                f16x8 af = *(const f16x8*)(Uf + ln * UST + k * 32 + lq * 8);
                aO = MFMA16(af, wD1r[k], aO);
                f16x8 b0 = *(const f16x8*)(GL + ((0 + tg) * 5 + k) * 512 + lane * 8);
                g0 = MFMA16(af, b0, g0);
                f16x8 b1 = *(const f16x8*)(GL + ((8 + tg) * 5 + k) * 512 + lane * 8);
                g1 = MFMA16(af, b1, g1);
                f16x8 b2 = *(const f16x8*)(GL + ((16 + tg) * 5 + k) * 512 + lane * 8);
                if (k == 0) g2i = MFMA16(af, b2, g2i);
                else        g2h = MFMA16(af, b2, g2h);
            }
            int c = tg * 16 + ln;
            float bD = bD1L[c];
            float br = bIHL[c] + bHHL[c];
            float bz = bIHL[128 + c] + bHHL[128 + c];
            float bgi = bIHL[256 + c], bgh = bHHL[256 + c];
#pragma unroll
            for (int j = 0; j < 4; ++j) {
                int row = lq * 4 + j;
                aAf[row * AST + c] = f2h(fmaxf(aO[j] + bD, 0.f));
                float rr = sigmoidf_(g0[j] + br);
                float zz = sigmoidf_(g1[j] + bz);
                float nn = tanhf(fmaf(rr, g2h[j] + bgh, g2i[j] + bgi));
                float hold = h2f(Uf[row * UST + 32 + c]);
                hn[j] = fmaf(zz, hold - nn, nn);
            }
        }
        __syncthreads();

        // ---- P7: h write + dec2 (pinned D2) ----
        {
            int c = tg * 16 + ln;
#pragma unroll
            for (int j = 0; j < 4; ++j)
                Uf[(lq * 4 + j) * UST + 32 + c] = f2h(hn[j]);
            f32x4 acc = {0,0,0,0};
#pragma unroll
            for (int k = 0; k < 4; ++k) {
                f16x8 af = *(const f16x8*)(aAf + ln * AST + k * 32 + lq * 8);
                acc = MFMA16(af, wD2r[k], acc);
            }
            float bE = bD2L[c];
#pragma unroll
            for (int j = 0; j < 4; ++j)
                aBf[(lq * 4 + j) * AST + c] = f2h(fmaxf(acc[j] + bE, 0.f));
        }
        __syncthreads();
    }

    // ---- epilogue: dec-heads + NLL for step NS-1 ----
    if (wave == 0) {
        f32x4 acc = {0, 0, 0, 0};
#pragma unroll
        for (int k = 0; k < 4; ++k) {
            f16x8 af = *(const f16x8*)(aBf + ln * AST + k * 32 + lq * 8);
            f16x8 bf = W8[OF_DH / 8 + k * 64 + lane];
            acc = MFMA16(af, bf, acc);
        }
        if (ln < 4) {
            float bb = bDHl[ln];
#pragma unroll
            for (int j = 0; j < 4; ++j) {
                int row = lq * 4 + j;
                float v = acc[j] + bb;
                if (ln < 2) dmuL[row][ln] = v;
                else        dsdL[row][ln - 2] = softplusf_(v);
            }
        }
        asm volatile("s_waitcnt lgkmcnt(0)" ::: "memory");
        if (lane < 32) {
            int r = lane >> 1, xd = lane & 1;
            float d = xf2[(NS - 1) & 1][r][xd] - dmuL[r][xd];
            float sd = dsdL[r][xd];
            nll_acc += 0.5f * (d * d / (sd * sd) + 2.f * logf(sd) + LOG2PI_F);
        }
    }

    // ---- block reduction ----
    __syncthreads();
    {
        float k = kl_acc, n = nll_acc;
        k += __shfl_xor(k, 1);  n += __shfl_xor(n, 1);
        k += __shfl_xor(k, 2);  n += __shfl_xor(n, 2);
        k += __shfl_xor(k, 4);  n += __shfl_xor(n, 4);
        k += __shfl_xor(k, 8);  n += __shfl_xor(n, 8);
        k += __shfl_xor(k, 16); n += __shfl_xor(n, 16);
        k += __shfl_xor(k, 32); n += __shfl_xor(n, 32);
        if (lane == 0) { redW[wave] = k; redW[16 + wave] = n; }
    }
    __syncthreads();
    if (tid == 0) {
        float s = 0.f, s2 = 0.f;
#pragma unroll
        for (int i = 0; i < 8; ++i) { s += redW[i]; s2 += redW[16 + i]; }
        p.partials[blockIdx.x] = s;
        p.partials[NWG + blockIdx.x] = s2;
    }
}

// ---------------- prep: pack weights into B-fragment order ----------------
struct PrepP {
    const float* eW1; const float* pW1; const float* dW1;
    const float* wih; const float* whh;
    const float* eW2; const float* pW2; const float* dW2;
    const float* hW[4];
    const float* dmW; const float* dsW;
    u16* dst;
};

__global__ void prep4(PrepP pp) {
    const int jNT[12]  = {8,8,8,24, 8,8,8, 1,1,1,1, 1};
    const int jKST[12] = {5,5,5,5, 4,4,4, 4,4,4,4, 4};
    const int jOFS[12] = {OF_E1,OF_P1,OF_D1,OF_G, OF_E2,OF_P2,OF_D2,
                          OF_H,OF_H+2048,OF_H+4096,OF_H+6144, OF_DH};
    const int jkt[3]   = {140,138,154};

    int job = blockIdx.y;
    int nt = jNT[job], kst = jKST[job];
    int per_agent = nt * kst * 512;
    int total = A_ * per_agent;
    int idx = blockIdx.x * 256 + threadIdx.x;
    if (idx >= total) return;
    int a = idx / per_agent;
    int rem = idx - a * per_agent;
    int slot = rem >> 9;            // /512
    int within = rem & 511;
    int lane = within >> 3, j = within & 7;
    int ntile = slot / kst, kstep = slot - ntile * kst;
    int k = kstep * 32 + (lane >> 4) * 8 + j;
    int n = ntile * 16 + (lane & 15);

    float val = 0.f;
    if (job < 3) {
        int sk = -1;
        if (job == 0)      sk = (k < 12) ? k : (k >= 32 ? k - 20 : -1);
        else if (job == 1) sk = (k >= 2 && k < 12) ? k - 2 : (k >= 32 ? k - 22 : -1);
        else               sk = (k >= 2 && k < 28) ? k - 2 : (k >= 32 ? k - 6 : -1);
        const float* s = (job == 0) ? pp.eW1 : (job == 1) ? pp.pW1 : pp.dW1;
        if (sk >= 0) val = s[((size_t)a * jkt[job] + sk) * 128 + n];
    } else if (job == 3) {
        if (k < 2)                  val = pp.wih[((size_t)a * 384 + n) * 18 + k];
        else if (k >= 12 && k < 28) val = pp.wih[((size_t)a * 384 + n) * 18 + (k - 10)];
        else if (k >= 32)           val = pp.whh[((size_t)a * 384 + n) * 128 + (k - 32)];
    } else if (job < 7) {
        const float* s = (job == 4) ? pp.eW2 : (job == 5) ? pp.pW2 : pp.dW2;
        val = s[((size_t)a * 128 + k) * 128 + n];
    } else if (job < 11) {
        val = pp.hW[job - 7][((size_t)a * 128 + k) * 16 + n];
    } else {
        if (n < 2)      val = pp.dmW[((size_t)a * 128 + k) * 2 + n];
        else if (n < 4) val = pp.dsW[((size_t)a * 128 + k) * 2 + (n - 2)];
    }
    pp.dst[(size_t)a * AGE + jOFS[job] + rem] = f2h(val);
}

__global__ void finish_kernel(const float* __restrict__ partials, float* __restrict__ out) {
    int tid = threadIdx.x;   // 64 threads
    float k = (tid < NWG) ? partials[tid] : 0.f;
    float n = (tid < NWG) ? partials[NWG + tid] : 0.f;
    k += __shfl_xor(k, 1);  n += __shfl_xor(n, 1);
    k += __shfl_xor(k, 2);  n += __shfl_xor(n, 2);
    k += __shfl_xor(k, 4);  n += __shfl_xor(n, 4);
    k += __shfl_xor(k, 8);  n += __shfl_xor(n, 8);
    k += __shfl_xor(k, 16); n += __shfl_xor(n, 16);
    k += __shfl_xor(k, 32); n += __shfl_xor(n, 32);
    if (tid == 0) { out[0] = k; out[1] = n; }
}

extern "C" void kernel_launch(void* const* d_in, const int* in_sizes, int n_in,
                              void* d_out, int out_size, void* d_ws, size_t ws_size,
                              hipStream_t stream) {
    float* partials = (float*)d_ws;                 // 80 floats
    u16* wq = (u16*)((char*)d_ws + 4096);           // packed frags, ~1.78 MB

    PrepP pp;
    pp.eW1 = (const float*)d_in[2];
    pp.pW1 = (const float*)d_in[10];
    pp.dW1 = (const float*)d_in[18];
    pp.wih = (const float*)d_in[26];
    pp.whh = (const float*)d_in[27];
    pp.eW2 = (const float*)d_in[4];
    pp.pW2 = (const float*)d_in[12];
    pp.dW2 = (const float*)d_in[20];
    pp.hW[0] = (const float*)d_in[6];   // emW
    pp.hW[1] = (const float*)d_in[8];   // esW
    pp.hW[2] = (const float*)d_in[14];  // pmW
    pp.hW[3] = (const float*)d_in[16];  // psW
    pp.dmW = (const float*)d_in[22];
    pp.dsW = (const float*)d_in[24];
    pp.dst = wq;
    prep4<<<dim3(1200, 12), 256, 0, stream>>>(pp);

    PM p;
    p.y   = (const float*)d_in[0];
    p.eps = (const float*)d_in[1];
    p.eb1 = (const float*)d_in[3];  p.eb2 = (const float*)d_in[5];
    p.emb = (const float*)d_in[7];  p.esb = (const float*)d_in[9];
    p.pb1 = (const float*)d_in[11]; p.pb2 = (const float*)d_in[13];
    p.pmb = (const float*)d_in[15]; p.psb = (const float*)d_in[17];
    p.db1 = (const float*)d_in[19]; p.db2 = (const float*)d_in[21];
    p.dmb = (const float*)d_in[23]; p.dsb = (const float*)d_in[25];
    p.bih = (const float*)d_in[28]; p.bhh = (const float*)d_in[29];
    p.wq = wq;
    p.partials = partials;

    vrnn13<<<NWG, NTH, 0, stream>>>(p);
    finish_kernel<<<1, 64, 0, stream>>>(partials, (float*)d_out);
}

// Round 14
// 791.350 us; speedup vs baseline: 1.3974x; 1.0683x over previous
//
#include <hip/hip_runtime.h>
#include <math.h>

typedef unsigned int u32;
typedef unsigned short u16;

#define NS 128          // T-1 timesteps
#define A_ 5
#define B_ 128
#define NTH 512
#define BC 16
#define NWG 40          // 5 agents x 8 chunks of 16 rows
#define LOG2PI_F 1.8378770664093453f

// ---- B-fragment packed weight layout (u16 units), per agent ----
// frag order: [layer][ntile][kstep][lane 0..63][j 0..7], elem = W[k][n] with
// k = kstep*32 + (lane>>4)*8 + j, n = ntile*16 + (lane&15).   (verified R10-R13, absmax 0)
#define OF_E1 0         // 8 ntiles x 5 ksteps
#define OF_P1 20480
#define OF_D1 40960
#define OF_G  61440     // 24 ntiles x 5
#define OF_E2 122880    // 8 x 4
#define OF_P2 139264
#define OF_D2 155648
#define OF_H  172032    // 4 heads x (1 x 4)
#define OF_DH 180224    // 1 x 4 (cols: dm0 dm1 ds0 ds1, rest 0)
#define AGE   182272

typedef _Float16 f16x8 __attribute__((ext_vector_type(8)));
typedef float f32x4 __attribute__((ext_vector_type(4)));

__device__ __forceinline__ u16 f2h(float f) { _Float16 h = (_Float16)f; return __builtin_bit_cast(u16, h); }
__device__ __forceinline__ float h2f(u16 u) { return (float)__builtin_bit_cast(_Float16, u); }
__device__ __forceinline__ float softplusf_(float x) { return fmaxf(x, 0.f) + log1pf(expf(-fabsf(x))); }
__device__ __forceinline__ float sigmoidf_(float x) { return 1.f / (1.f + expf(-x)); }

#define MFMA16(af, bf, acc) __builtin_amdgcn_mfma_f32_16x16x32_f16((af), (bf), (acc), 0, 0, 0)
#define PINF8(v) asm volatile("" : "+v"(v))

#define UST 168   // Uf row stride (elems): 20*ln+4*lq banks -> 2-way max (free)
#define AST 168   // activation row stride: same class (was 136 = 8-way conflict)

struct PM {
    const float* __restrict__ y;
    const float* __restrict__ eps;
    const float* __restrict__ eb1; const float* __restrict__ eb2;
    const float* __restrict__ pb1; const float* __restrict__ pb2;
    const float* __restrict__ db1; const float* __restrict__ db2;
    const float* __restrict__ emb; const float* __restrict__ esb;
    const float* __restrict__ pmb; const float* __restrict__ psb;
    const float* __restrict__ dmb; const float* __restrict__ dsb;
    const float* __restrict__ bih; const float* __restrict__ bhh;
    const u16* __restrict__ wq;
    float* __restrict__ partials;
};

// (512,2): 2 waves/EU declared = geometric truth -> VGPR cap 256 (2048/CU pool).
// Pin ALL 27 per-wave B-frags (108 VGPR) -> zero L2 on GEMM critical path
// except P4 heads. G (GRU) stays LDS-resident.
__global__ void __launch_bounds__(NTH, 2) vrnn14(PM p) {
    const int tid = threadIdx.x;
    const int wave = tid >> 6;               // 0..7 = output tile group tg
    const int lane = tid & 63;
    const int ln = lane & 15;
    const int lq = lane >> 4;
    const int a = blockIdx.x >> 3;
    const int b0 = (blockIdx.x & 7) * BC;
    const int tg = wave;

    __shared__ __align__(16) u16 GL[61440];          // GRU B-frags, 120KB
    __shared__ __align__(16) u16 Uf[16 * UST];       // [x2 y10 z16 pad4 h128]
    __shared__ __align__(16) u16 aAf[16 * AST], aBf[16 * AST], aCf[16 * AST], aDf[16 * AST];
    __shared__ float mueL[16][17], sdeL[16][17], mupL[16][17], sdpL[16][17];
    __shared__ float xf2[2][16][2];                  // t-parity double buffer
    __shared__ float dmuL[16][2], dsdL[16][2];
    __shared__ float bE1L[128], bP1L[128], bD1L[128];
    __shared__ float bE2L[128], bP2L[128], bD2L[128];
    __shared__ float bIHL[384], bHHL[384], bHl[64], bDHl[4];
    __shared__ float redW[32];

    const f16x8* __restrict__ W8 = (const f16x8*)p.wq + (size_t)a * (AGE / 8);

    // ---- init: G to LDS, biases, zero U ----
    {
        const uint4* gsrc = (const uint4*)(p.wq + (size_t)a * AGE + OF_G);
        uint4* gdst = (uint4*)GL;
        for (int i = tid; i < 61440 / 8; i += NTH) gdst[i] = gsrc[i];
    }
    for (int i = tid; i < 16 * UST; i += NTH) Uf[i] = 0;
    if (tid < 128) {
        bE1L[tid] = p.eb1[a * 128 + tid]; bE2L[tid] = p.eb2[a * 128 + tid];
        bP1L[tid] = p.pb1[a * 128 + tid]; bP2L[tid] = p.pb2[a * 128 + tid];
        bD1L[tid] = p.db1[a * 128 + tid]; bD2L[tid] = p.db2[a * 128 + tid];
    }
    if (tid < 384) { bIHL[tid] = p.bih[a * 384 + tid]; bHHL[tid] = p.bhh[a * 384 + tid]; }
    if (tid < 64) {
        int h = tid >> 4, c = tid & 15;
        bHl[tid] = ((h == 0) ? p.emb : (h == 1) ? p.esb : (h == 2) ? p.pmb : p.psb)[a * 16 + c];
    }
    if (tid < 4) bDHl[tid] = (tid < 2) ? p.dmb[a * 2 + tid] : p.dsb[a * 2 + (tid - 2)];

    // ---- pinned t-invariant B-fragments: ALL per-wave tiles (27 frags) ----
    f16x8 wE1r[5], wP1r[5], wD1r[5], wE2r[4], wP2r[4], wD2r[4];
#pragma unroll
    for (int k = 0; k < 5; ++k) {
        wE1r[k] = W8[OF_E1 / 8 + (tg * 5 + k) * 64 + lane];
        wP1r[k] = W8[OF_P1 / 8 + (tg * 5 + k) * 64 + lane];
        wD1r[k] = W8[OF_D1 / 8 + (tg * 5 + k) * 64 + lane];
    }
#pragma unroll
    for (int k = 0; k < 4; ++k) {
        wE2r[k] = W8[OF_E2 / 8 + (tg * 4 + k) * 64 + lane];
        wP2r[k] = W8[OF_P2 / 8 + (tg * 4 + k) * 64 + lane];
        wD2r[k] = W8[OF_D2 / 8 + (tg * 4 + k) * 64 + lane];
    }
#pragma unroll
    for (int k = 0; k < 5; ++k) { PINF8(wE1r[k]); PINF8(wP1r[k]); PINF8(wD1r[k]); }
#pragma unroll
    for (int k = 0; k < 4; ++k) { PINF8(wE2r[k]); PINF8(wP2r[k]); PINF8(wD2r[k]); }

    // ---- loader roles: waves 4-6 (tid 256..447) ----
    const int tl = tid - 256;
    const int ry = (tl >= 0) ? tl / 10 : 0, jy = (tl >= 0) ? tl - (tl / 10) * 10 : 0;   // tl<160
    const int rx = (tl - 160) >> 1, xdx = (tl - 160) & 1;                                // 160<=tl<192
    const int re = tid >> 4, ze = tid & 15;                                              // tid<256 (P5)

    // ---- prefetch t=0 inputs ----
    float ypre = 0.f, xpre = 0.f, epre = 0.f;
    if (tl >= 0 && tl < 160) ypre = p.y[0 * (B_ * 10) + (b0 + ry) * 10 + jy];
    else if (tl >= 160 && tl < 192) xpre = p.y[1 * (B_ * 10) + (b0 + rx) * 10 + a * 2 + xdx];
    if (tid < 256) epre = p.eps[(((size_t)0 * A_ + a) * B_ + (b0 + re)) * 16 + ze];

    float kl_acc = 0.f, nll_acc = 0.f;

    __syncthreads();   // GL/bias init + pins done before first use

#pragma unroll 1
    for (int t = 0; t < NS; ++t) {
        const int tn = (t + 1 < NS) ? t + 1 : t;
        // ---- P1 phase: loaders commit y/x; wave 0 does dec-heads+NLL for t-1 ----
        if (tl >= 0 && tl < 160) {
            Uf[ry * UST + 2 + jy] = f2h(ypre);
            ypre = p.y[tn * (B_ * 10) + (b0 + ry) * 10 + jy];
        } else if (tl >= 160 && tl < 192) {
            Uf[rx * UST + xdx] = f2h(xpre);
            xf2[t & 1][rx][xdx] = xpre;
            xpre = p.y[(tn + 1) * (B_ * 10) + (b0 + rx) * 10 + a * 2 + xdx];
        }
        if (wave == 0 && t > 0) {
            f32x4 acc = {0, 0, 0, 0};
#pragma unroll
            for (int k = 0; k < 4; ++k) {
                f16x8 af = *(const f16x8*)(aBf + ln * AST + k * 32 + lq * 8);
                f16x8 bf = W8[OF_DH / 8 + k * 64 + lane];
                acc = MFMA16(af, bf, acc);
            }
            if (ln < 4) {
                float bb = bDHl[ln];
#pragma unroll
                for (int j = 0; j < 4; ++j) {
                    int row = lq * 4 + j;
                    float v = acc[j] + bb;
                    if (ln < 2) dmuL[row][ln] = v;
                    else        dsdL[row][ln - 2] = softplusf_(v);
                }
            }
            asm volatile("s_waitcnt lgkmcnt(0)" ::: "memory");  // same-wave LDS RAW
            if (lane < 32) {
                int r = lane >> 1, xd = lane & 1;
                float d = xf2[(t - 1) & 1][r][xd] - dmuL[r][xd];
                float sd = dsdL[r][xd];
                nll_acc += 0.5f * (d * d / (sd * sd) + 2.f * logf(sd) + LOG2PI_F);
            }
        }
        __syncthreads();

        // ---- P2: enc1 (pinned E1) + pri1 (pinned P1) ----
        {
            f32x4 accE = {0,0,0,0}, accP = {0,0,0,0};
#pragma unroll
            for (int k = 0; k < 5; ++k) {
                f16x8 af = *(const f16x8*)(Uf + ln * UST + k * 32 + lq * 8);
                accE = MFMA16(af, wE1r[k], accE);
                accP = MFMA16(af, wP1r[k], accP);
            }
            int c = tg * 16 + ln;
            float bE = bE1L[c], bP = bP1L[c];
#pragma unroll
            for (int j = 0; j < 4; ++j) {
                int row = lq * 4 + j;
                aAf[row * AST + c] = f2h(fmaxf(accE[j] + bE, 0.f));
                aCf[row * AST + c] = f2h(fmaxf(accP[j] + bP, 0.f));
            }
        }
        __syncthreads();

        // ---- P3: enc2 (pinned E2) + pri2 (pinned P2) ----
        {
            f32x4 accE = {0,0,0,0}, accP = {0,0,0,0};
#pragma unroll
            for (int k = 0; k < 4; ++k) {
                f16x8 a1 = *(const f16x8*)(aAf + ln * AST + k * 32 + lq * 8);
                f16x8 a2 = *(const f16x8*)(aCf + ln * AST + k * 32 + lq * 8);
                accE = MFMA16(a1, wE2r[k], accE);
                accP = MFMA16(a2, wP2r[k], accP);
            }
            int c = tg * 16 + ln;
            float bE = bE2L[c], bP = bP2L[c];
#pragma unroll
            for (int j = 0; j < 4; ++j) {
                int row = lq * 4 + j;
                aBf[row * AST + c] = f2h(fmaxf(accE[j] + bE, 0.f));
                aDf[row * AST + c] = f2h(fmaxf(accP[j] + bP, 0.f));
            }
        }
        __syncthreads();

        // ---- P4: 4 gaussian heads (waves 0-3; B from L2 — only stream left) ----
        if (wave < 4) {
            const u16* src = (wave < 2) ? aBf : aDf;
            f32x4 acc = {0,0,0,0};
#pragma unroll
            for (int k = 0; k < 4; ++k) {
                f16x8 af = *(const f16x8*)(src + ln * AST + k * 32 + lq * 8);
                f16x8 bf = W8[OF_H / 8 + wave * 256 + k * 64 + lane];
                acc = MFMA16(af, bf, acc);
            }
            float bb = bHl[wave * 16 + ln];
#pragma unroll
            for (int j = 0; j < 4; ++j) {
                int row = lq * 4 + j;
                float v = acc[j] + bb;
                if (wave == 0)      mueL[row][ln] = v;
                else if (wave == 1) sdeL[row][ln] = softplusf_(v);
                else if (wave == 2) mupL[row][ln] = v;
                else                sdpL[row][ln] = softplusf_(v);
            }
        }
        __syncthreads();

        // ---- P5: z sample + KL (256 threads) ----
        if (tid < 256) {
            float em = mueL[re][ze], es = sdeL[re][ze], pm = mupL[re][ze], ps = sdpL[re][ze];
            float zv = fmaf(epre, es, em);
            Uf[re * UST + 12 + ze] = f2h(zv);
            float dm = em - pm;
            kl_acc += 0.5f * (2.f * (logf(ps) - logf(es)) + (es * es + dm * dm) / (ps * ps) - 1.f);
            epre = p.eps[(((size_t)tn * A_ + a) * B_ + (b0 + re)) * 16 + ze];
        }
        __syncthreads();

        // ---- P6: dec1 (pinned D1) + GRU gates (GL LDS) ----
        float hn[4];
        {
            f32x4 aO = {0,0,0,0}, g0 = {0,0,0,0}, g1 = {0,0,0,0};
            f32x4 g2i = {0,0,0,0}, g2h = {0,0,0,0};
#pragma unroll
            for (int k = 0; k < 5; ++k) {
                f16x8 af = *(const f16x8*)(Uf + ln * UST + k * 32 + lq * 8);
                aO = MFMA16(af, wD1r[k], aO);
                f16x8 b0 = *(const f16x8*)(GL + ((0 + tg) * 5 + k) * 512 + lane * 8);
                g0 = MFMA16(af, b0, g0);
                f16x8 b1 = *(const f16x8*)(GL + ((8 + tg) * 5 + k) * 512 + lane * 8);
                g1 = MFMA16(af, b1, g1);
                f16x8 b2 = *(const f16x8*)(GL + ((16 + tg) * 5 + k) * 512 + lane * 8);
                if (k == 0) g2i = MFMA16(af, b2, g2i);
                else        g2h = MFMA16(af, b2, g2h);
            }
            int c = tg * 16 + ln;
            float bD = bD1L[c];
            float br = bIHL[c] + bHHL[c];
            float bz = bIHL[128 + c] + bHHL[128 + c];
            float bgi = bIHL[256 + c], bgh = bHHL[256 + c];
#pragma unroll
            for (int j = 0; j < 4; ++j) {
                int row = lq * 4 + j;
                aAf[row * AST + c] = f2h(fmaxf(aO[j] + bD, 0.f));
                float rr = sigmoidf_(g0[j] + br);
                float zz = sigmoidf_(g1[j] + bz);
                float nn = tanhf(fmaf(rr, g2h[j] + bgh, g2i[j] + bgi));
                float hold = h2f(Uf[row * UST + 32 + c]);
                hn[j] = fmaf(zz, hold - nn, nn);
            }
        }
        __syncthreads();

        // ---- P7: h write + dec2 (pinned D2) ----
        {
            int c = tg * 16 + ln;
#pragma unroll
            for (int j = 0; j < 4; ++j)
                Uf[(lq * 4 + j) * UST + 32 + c] = f2h(hn[j]);
            f32x4 acc = {0,0,0,0};
#pragma unroll
            for (int k = 0; k < 4; ++k) {
                f16x8 af = *(const f16x8*)(aAf + ln * AST + k * 32 + lq * 8);
                acc = MFMA16(af, wD2r[k], acc);
            }
            float bE = bD2L[c];
#pragma unroll
            for (int j = 0; j < 4; ++j)
                aBf[(lq * 4 + j) * AST + c] = f2h(fmaxf(acc[j] + bE, 0.f));
        }
        __syncthreads();
    }

    // ---- epilogue: dec-heads + NLL for step NS-1 ----
    if (wave == 0) {
        f32x4 acc = {0, 0, 0, 0};
#pragma unroll
        for (int k = 0; k < 4; ++k) {
            f16x8 af = *(const f16x8*)(aBf + ln * AST + k * 32 + lq * 8);
            f16x8 bf = W8[OF_DH / 8 + k * 64 + lane];
            acc = MFMA16(af, bf, acc);
        }
        if (ln < 4) {
            float bb = bDHl[ln];
#pragma unroll
            for (int j = 0; j < 4; ++j) {
                int row = lq * 4 + j;
                float v = acc[j] + bb;
                if (ln < 2) dmuL[row][ln] = v;
                else        dsdL[row][ln - 2] = softplusf_(v);
            }
        }
        asm volatile("s_waitcnt lgkmcnt(0)" ::: "memory");
        if (lane < 32) {
            int r = lane >> 1, xd = lane & 1;
            float d = xf2[(NS - 1) & 1][r][xd] - dmuL[r][xd];
            float sd = dsdL[r][xd];
            nll_acc += 0.5f * (d * d / (sd * sd) + 2.f * logf(sd) + LOG2PI_F);
        }
    }

    // ---- block reduction ----
    __syncthreads();
    {
        float k = kl_acc, n = nll_acc;
        k += __shfl_xor(k, 1);  n += __shfl_xor(n, 1);
        k += __shfl_xor(k, 2);  n += __shfl_xor(n, 2);
        k += __shfl_xor(k, 4);  n += __shfl_xor(n, 4);
        k += __shfl_xor(k, 8);  n += __shfl_xor(n, 8);
        k += __shfl_xor(k, 16); n += __shfl_xor(n, 16);
        k += __shfl_xor(k, 32); n += __shfl_xor(n, 32);
        if (lane == 0) { redW[wave] = k; redW[16 + wave] = n; }
    }
    __syncthreads();
    if (tid == 0) {
        float s = 0.f, s2 = 0.f;
#pragma unroll
        for (int i = 0; i < 8; ++i) { s += redW[i]; s2 += redW[16 + i]; }
        p.partials[blockIdx.x] = s;
        p.partials[NWG + blockIdx.x] = s2;
    }
}

// ---------------- prep: pack weights into B-fragment order ----------------
struct PrepP {
    const float* eW1; const float* pW1; const float* dW1;
    const float* wih; const float* whh;
    const float* eW2; const float* pW2; const float* dW2;
    const float* hW[4];
    const float* dmW; const float* dsW;
    u16* dst;
};

__global__ void prep4(PrepP pp) {
    const int jNT[12]  = {8,8,8,24, 8,8,8, 1,1,1,1, 1};
    const int jKST[12] = {5,5,5,5, 4,4,4, 4,4,4,4, 4};
    const int jOFS[12] = {OF_E1,OF_P1,OF_D1,OF_G, OF_E2,OF_P2,OF_D2,
                          OF_H,OF_H+2048,OF_H+4096,OF_H+6144, OF_DH};
    const int jkt[3]   = {140,138,154};

    int job = blockIdx.y;
    int nt = jNT[job], kst = jKST[job];
    int per_agent = nt * kst * 512;
    int total = A_ * per_agent;
    int idx = blockIdx.x * 256 + threadIdx.x;
    if (idx >= total) return;
    int a = idx / per_agent;
    int rem = idx - a * per_agent;
    int slot = rem >> 9;            // /512
    int within = rem & 511;
    int lane = within >> 3, j = within & 7;
    int ntile = slot / kst, kstep = slot - ntile * kst;
    int k = kstep * 32 + (lane >> 4) * 8 + j;
    int n = ntile * 16 + (lane & 15);

    float val = 0.f;
    if (job < 3) {
        int sk = -1;
        if (job == 0)      sk = (k < 12) ? k : (k >= 32 ? k - 20 : -1);
        else if (job == 1) sk = (k >= 2 && k < 12) ? k - 2 : (k >= 32 ? k - 22 : -1);
        else               sk = (k >= 2 && k < 28) ? k - 2 : (k >= 32 ? k - 6 : -1);
        const float* s = (job == 0) ? pp.eW1 : (job == 1) ? pp.pW1 : pp.dW1;
        if (sk >= 0) val = s[((size_t)a * jkt[job] + sk) * 128 + n];
    } else if (job == 3) {
        if (k < 2)                  val = pp.wih[((size_t)a * 384 + n) * 18 + k];
        else if (k >= 12 && k < 28) val = pp.wih[((size_t)a * 384 + n) * 18 + (k - 10)];
        else if (k >= 32)           val = pp.whh[((size_t)a * 384 + n) * 128 + (k - 32)];
    } else if (job < 7) {
        const float* s = (job == 4) ? pp.eW2 : (job == 5) ? pp.pW2 : pp.dW2;
        val = s[((size_t)a * 128 + k) * 128 + n];
    } else if (job < 11) {
        val = pp.hW[job - 7][((size_t)a * 128 + k) * 16 + n];
    } else {
        if (n < 2)      val = pp.dmW[((size_t)a * 128 + k) * 2 + n];
        else if (n < 4) val = pp.dsW[((size_t)a * 128 + k) * 2 + (n - 2)];
    }
    pp.dst[(size_t)a * AGE + jOFS[job] + rem] = f2h(val);
}

__global__ void finish_kernel(const float* __restrict__ partials, float* __restrict__ out) {
    int tid = threadIdx.x;   // 64 threads
    float k = (tid < NWG) ? partials[tid] : 0.f;
    float n = (tid < NWG) ? partials[NWG + tid] : 0.f;
    k += __shfl_xor(k, 1);  n += __shfl_xor(n, 1);
    k += __shfl_xor(k, 2);  n += __shfl_xor(n, 2);
    k += __shfl_xor(k, 4);  n += __shfl_xor(n, 4);
    k += __shfl_xor(k, 8);  n += __shfl_xor(n, 8);
    k += __shfl_xor(k, 16); n += __shfl_xor(n, 16);
    k += __shfl_xor(k, 32); n += __shfl_xor(n, 32);
    if (tid == 0) { out[0] = k; out[1] = n; }
}

extern "C" void kernel_launch(void* const* d_in, const int* in_sizes, int n_in,
                              void* d_out, int out_size, void* d_ws, size_t ws_size,
                              hipStream_t stream) {
    float* partials = (float*)d_ws;                 // 80 floats
    u16* wq = (u16*)((char*)d_ws + 4096);           // packed frags, ~1.78 MB

    PrepP pp;
    pp.eW1 = (const float*)d_in[2];
    pp.pW1 = (const float*)d_in[10];
    pp.dW1 = (const float*)d_in[18];
    pp.wih = (const float*)d_in[26];
    pp.whh = (const float*)d_in[27];
    pp.eW2 = (const float*)d_in[4];
    pp.pW2 = (const float*)d_in[12];
    pp.dW2 = (const float*)d_in[20];
    pp.hW[0] = (const float*)d_in[6];   // emW
    pp.hW[1] = (const float*)d_in[8];   // esW
    pp.hW[2] = (const float*)d_in[14];  // pmW
    pp.hW[3] = (const float*)d_in[16];  // psW
    pp.dmW = (const float*)d_in[22];
    pp.dsW = (const float*)d_in[24];
    pp.dst = wq;
    prep4<<<dim3(1200, 12), 256, 0, stream>>>(pp);

    PM p;
    p.y   = (const float*)d_in[0];
    p.eps = (const float*)d_in[1];
    p.eb1 = (const float*)d_in[3];  p.eb2 = (const float*)d_in[5];
    p.emb = (const float*)d_in[7];  p.esb = (const float*)d_in[9];
    p.pb1 = (const float*)d_in[11]; p.pb2 = (const float*)d_in[13];
    p.pmb = (const float*)d_in[15]; p.psb = (const float*)d_in[17];
    p.db1 = (const float*)d_in[19]; p.db2 = (const float*)d_in[21];
    p.dmb = (const float*)d_in[23]; p.dsb = (const float*)d_in[25];
    p.bih = (const float*)d_in[28]; p.bhh = (const float*)d_in[29];
    p.wq = wq;
    p.partials = partials;

    vrnn14<<<NWG, NTH, 0, stream>>>(p);
    finish_kernel<<<1, 64, 0, stream>>>(partials, (float*)d_out);
}

// Round 15
// 514.356 us; speedup vs baseline: 2.1500x; 1.5385x over previous
//
#include <hip/hip_runtime.h>
#include <math.h>

typedef unsigned int u32;
typedef unsigned short u16;

#define NS 128          // T-1 timesteps
#define A_ 5
#define B_ 128
#define NTH 512
#define BC 16
#define NWG 40          // 5 agents x 8 chunks of 16 rows
#define LOG2PI_F 1.8378770664093453f

// ---- B-fragment packed weight layout (u16 units), per agent ----
// frag order: [layer][ntile][kstep][lane 0..63][j 0..7], elem = W[k][n] with
// k = kstep*32 + (lane>>4)*8 + j, n = ntile*16 + (lane&15).   (verified R10-R14, absmax 0)
#define OF_E1 0         // 8 ntiles x 5 ksteps
#define OF_P1 20480
#define OF_D1 40960
#define OF_G  61440     // 24 ntiles x 5
#define OF_E2 122880    // 8 x 4
#define OF_P2 139264
#define OF_D2 155648
#define OF_H  172032    // 4 heads x (1 x 4)
#define OF_DH 180224    // 1 x 4 (cols: dm0 dm1 ds0 ds1, rest 0)
#define AGE   182272

typedef _Float16 f16x8 __attribute__((ext_vector_type(8)));
typedef float f32x4 __attribute__((ext_vector_type(4)));

__device__ __forceinline__ u16 f2h(float f) { _Float16 h = (_Float16)f; return __builtin_bit_cast(u16, h); }
__device__ __forceinline__ float h2f(u16 u) { return (float)__builtin_bit_cast(_Float16, u); }

// ---- fast transcendentals: v_exp/v_log/v_rcp based (error ~1e-6 abs,
// threshold is 5283 absolute -> orders of magnitude of headroom) ----
__device__ __forceinline__ float frcp_(float x) { return __builtin_amdgcn_rcpf(x); }
__device__ __forceinline__ float fsig_(float x) { return frcp_(1.f + __expf(-x)); }        // inf-safe
__device__ __forceinline__ float ftanh_(float x) { return 1.f - 2.f * frcp_(1.f + __expf(2.f * x)); }
__device__ __forceinline__ float fsoftplus_(float x) {
    return fmaxf(x, 0.f) + __logf(1.f + __expf(-fabsf(x)));
}

#define MFMA16(af, bf, acc) __builtin_amdgcn_mfma_f32_16x16x32_f16((af), (bf), (acc), 0, 0, 0)
#define PINF8(v) asm volatile("" : "+v"(v))

#define UST 168   // Uf row stride (elems)
#define AST 168   // activation row stride

struct PM {
    const float* __restrict__ y;
    const float* __restrict__ eps;
    const float* __restrict__ eb1; const float* __restrict__ eb2;
    const float* __restrict__ pb1; const float* __restrict__ pb2;
    const float* __restrict__ db1; const float* __restrict__ db2;
    const float* __restrict__ emb; const float* __restrict__ esb;
    const float* __restrict__ pmb; const float* __restrict__ psb;
    const float* __restrict__ dmb; const float* __restrict__ dsb;
    const float* __restrict__ bih; const float* __restrict__ bhh;
    const u16* __restrict__ wq;
    float* __restrict__ partials;
};

// R14 base + fast transcendentals + pin-swap (H pinned for critical-path P4,
// D2 streamed in all-waves-active P7).
__global__ void __launch_bounds__(NTH, 2) vrnn15(PM p) {
    const int tid = threadIdx.x;
    const int wave = tid >> 6;               // 0..7 = output tile group tg
    const int lane = tid & 63;
    const int ln = lane & 15;
    const int lq = lane >> 4;
    const int a = blockIdx.x >> 3;
    const int b0 = (blockIdx.x & 7) * BC;
    const int tg = wave;

    __shared__ __align__(16) u16 GL[61440];          // GRU B-frags, 120KB
    __shared__ __align__(16) u16 Uf[16 * UST];       // [x2 y10 z16 pad4 h128]
    __shared__ __align__(16) u16 aAf[16 * AST], aBf[16 * AST], aCf[16 * AST], aDf[16 * AST];
    __shared__ float mueL[16][17], sdeL[16][17], mupL[16][17], sdpL[16][17];
    __shared__ float xf2[2][16][2];                  // t-parity double buffer
    __shared__ float dmuL[16][2], dsdL[16][2];
    __shared__ float bE1L[128], bP1L[128], bD1L[128];
    __shared__ float bE2L[128], bP2L[128], bD2L[128];
    __shared__ float bIHL[384], bHHL[384], bHl[64], bDHl[4];
    __shared__ float redW[32];

    const f16x8* __restrict__ W8 = (const f16x8*)p.wq + (size_t)a * (AGE / 8);

    // ---- init: G to LDS, biases, zero U ----
    {
        const uint4* gsrc = (const uint4*)(p.wq + (size_t)a * AGE + OF_G);
        uint4* gdst = (uint4*)GL;
        for (int i = tid; i < 61440 / 8; i += NTH) gdst[i] = gsrc[i];
    }
    for (int i = tid; i < 16 * UST; i += NTH) Uf[i] = 0;
    if (tid < 128) {
        bE1L[tid] = p.eb1[a * 128 + tid]; bE2L[tid] = p.eb2[a * 128 + tid];
        bP1L[tid] = p.pb1[a * 128 + tid]; bP2L[tid] = p.pb2[a * 128 + tid];
        bD1L[tid] = p.db1[a * 128 + tid]; bD2L[tid] = p.db2[a * 128 + tid];
    }
    if (tid < 384) { bIHL[tid] = p.bih[a * 384 + tid]; bHHL[tid] = p.bhh[a * 384 + tid]; }
    if (tid < 64) {
        int h = tid >> 4, c = tid & 15;
        bHl[tid] = ((h == 0) ? p.emb : (h == 1) ? p.esb : (h == 2) ? p.pmb : p.psb)[a * 16 + c];
    }
    if (tid < 4) bDHl[tid] = (tid < 2) ? p.dmb[a * 2 + tid] : p.dsb[a * 2 + (tid - 2)];

    // ---- pinned t-invariant B-fragments: E1/P1/D1/E2/P2 + heads H (27 frags) ----
    f16x8 wE1r[5], wP1r[5], wD1r[5], wE2r[4], wP2r[4], wHr[4];
#pragma unroll
    for (int k = 0; k < 5; ++k) {
        wE1r[k] = W8[OF_E1 / 8 + (tg * 5 + k) * 64 + lane];
        wP1r[k] = W8[OF_P1 / 8 + (tg * 5 + k) * 64 + lane];
        wD1r[k] = W8[OF_D1 / 8 + (tg * 5 + k) * 64 + lane];
    }
#pragma unroll
    for (int k = 0; k < 4; ++k) {
        wE2r[k] = W8[OF_E2 / 8 + (tg * 4 + k) * 64 + lane];
        wP2r[k] = W8[OF_P2 / 8 + (tg * 4 + k) * 64 + lane];
        wHr[k]  = W8[OF_H / 8 + (tg & 3) * 256 + k * 64 + lane];   // head (wave&3)
    }
#pragma unroll
    for (int k = 0; k < 5; ++k) { PINF8(wE1r[k]); PINF8(wP1r[k]); PINF8(wD1r[k]); }
#pragma unroll
    for (int k = 0; k < 4; ++k) { PINF8(wE2r[k]); PINF8(wP2r[k]); PINF8(wHr[k]); }

    // ---- loader roles: waves 4-6 (tid 256..447) ----
    const int tl = tid - 256;
    const int ry = (tl >= 0) ? tl / 10 : 0, jy = (tl >= 0) ? tl - (tl / 10) * 10 : 0;   // tl<160
    const int rx = (tl - 160) >> 1, xdx = (tl - 160) & 1;                                // 160<=tl<192
    const int re = tid >> 4, ze = tid & 15;                                              // tid<256 (P5)

    // ---- prefetch t=0 inputs ----
    float ypre = 0.f, xpre = 0.f, epre = 0.f;
    if (tl >= 0 && tl < 160) ypre = p.y[0 * (B_ * 10) + (b0 + ry) * 10 + jy];
    else if (tl >= 160 && tl < 192) xpre = p.y[1 * (B_ * 10) + (b0 + rx) * 10 + a * 2 + xdx];
    if (tid < 256) epre = p.eps[(((size_t)0 * A_ + a) * B_ + (b0 + re)) * 16 + ze];

    float kl_acc = 0.f, nll_acc = 0.f;

    __syncthreads();   // GL/bias init + pins done before first use

#pragma unroll 1
    for (int t = 0; t < NS; ++t) {
        const int tn = (t + 1 < NS) ? t + 1 : t;
        // ---- P1 phase: loaders commit y/x; wave 0 does dec-heads+NLL for t-1 ----
        if (tl >= 0 && tl < 160) {
            Uf[ry * UST + 2 + jy] = f2h(ypre);
            ypre = p.y[tn * (B_ * 10) + (b0 + ry) * 10 + jy];
        } else if (tl >= 160 && tl < 192) {
            Uf[rx * UST + xdx] = f2h(xpre);
            xf2[t & 1][rx][xdx] = xpre;
            xpre = p.y[(tn + 1) * (B_ * 10) + (b0 + rx) * 10 + a * 2 + xdx];
        }
        if (wave == 0 && t > 0) {
            f32x4 acc = {0, 0, 0, 0};
#pragma unroll
            for (int k = 0; k < 4; ++k) {
                f16x8 af = *(const f16x8*)(aBf + ln * AST + k * 32 + lq * 8);
                f16x8 bf = W8[OF_DH / 8 + k * 64 + lane];
                acc = MFMA16(af, bf, acc);
            }
            if (ln < 4) {
                float bb = bDHl[ln];
#pragma unroll
                for (int j = 0; j < 4; ++j) {
                    int row = lq * 4 + j;
                    float v = acc[j] + bb;
                    if (ln < 2) dmuL[row][ln] = v;
                    else        dsdL[row][ln - 2] = fsoftplus_(v);
                }
            }
            asm volatile("s_waitcnt lgkmcnt(0)" ::: "memory");  // same-wave LDS RAW
            if (lane < 32) {
                int r = lane >> 1, xd = lane & 1;
                float d = xf2[(t - 1) & 1][r][xd] - dmuL[r][xd];
                float isd = frcp_(dsdL[r][xd]);
                nll_acc += 0.5f * (d * d * isd * isd - 2.f * __logf(isd) + LOG2PI_F);
            }
        }
        __syncthreads();

        // ---- P2: enc1 (pinned E1) + pri1 (pinned P1) ----
        {
            f32x4 accE = {0,0,0,0}, accP = {0,0,0,0};
#pragma unroll
            for (int k = 0; k < 5; ++k) {
                f16x8 af = *(const f16x8*)(Uf + ln * UST + k * 32 + lq * 8);
                accE = MFMA16(af, wE1r[k], accE);
                accP = MFMA16(af, wP1r[k], accP);
            }
            int c = tg * 16 + ln;
            float bE = bE1L[c], bP = bP1L[c];
#pragma unroll
            for (int j = 0; j < 4; ++j) {
                int row = lq * 4 + j;
                aAf[row * AST + c] = f2h(fmaxf(accE[j] + bE, 0.f));
                aCf[row * AST + c] = f2h(fmaxf(accP[j] + bP, 0.f));
            }
        }
        __syncthreads();

        // ---- P3: enc2 (pinned E2) + pri2 (pinned P2) ----
        {
            f32x4 accE = {0,0,0,0}, accP = {0,0,0,0};
#pragma unroll
            for (int k = 0; k < 4; ++k) {
                f16x8 a1 = *(const f16x8*)(aAf + ln * AST + k * 32 + lq * 8);
                f16x8 a2 = *(const f16x8*)(aCf + ln * AST + k * 32 + lq * 8);
                accE = MFMA16(a1, wE2r[k], accE);
                accP = MFMA16(a2, wP2r[k], accP);
            }
            int c = tg * 16 + ln;
            float bE = bE2L[c], bP = bP2L[c];
#pragma unroll
            for (int j = 0; j < 4; ++j) {
                int row = lq * 4 + j;
                aBf[row * AST + c] = f2h(fmaxf(accE[j] + bE, 0.f));
                aDf[row * AST + c] = f2h(fmaxf(accP[j] + bP, 0.f));
            }
        }
        __syncthreads();

        // ---- P4: 4 gaussian heads (waves 0-3; pinned H) ----
        if (wave < 4) {
            const u16* src = (wave < 2) ? aBf : aDf;
            f32x4 acc = {0,0,0,0};
#pragma unroll
            for (int k = 0; k < 4; ++k) {
                f16x8 af = *(const f16x8*)(src + ln * AST + k * 32 + lq * 8);
                acc = MFMA16(af, wHr[k], acc);
            }
            float bb = bHl[wave * 16 + ln];
#pragma unroll
            for (int j = 0; j < 4; ++j) {
                int row = lq * 4 + j;
                float v = acc[j] + bb;
                if (wave == 0)      mueL[row][ln] = v;
                else if (wave == 1) sdeL[row][ln] = fsoftplus_(v);
                else if (wave == 2) mupL[row][ln] = v;
                else                sdpL[row][ln] = fsoftplus_(v);
            }
        }
        __syncthreads();

        // ---- P5: z sample + KL (256 threads) ----
        if (tid < 256) {
            float em = mueL[re][ze], es = sdeL[re][ze], pm = mupL[re][ze], ps = sdpL[re][ze];
            float zv = fmaf(epre, es, em);
            Uf[re * UST + 12 + ze] = f2h(zv);
            float dm = em - pm;
            float ips = frcp_(ps);
            kl_acc += 0.5f * (2.f * __logf(ps * frcp_(es)) + (es * es + dm * dm) * ips * ips - 1.f);
            epre = p.eps[(((size_t)tn * A_ + a) * B_ + (b0 + re)) * 16 + ze];
        }
        __syncthreads();

        // ---- P6: dec1 (pinned D1) + GRU gates (GL LDS) ----
        float hn[4];
        {
            f32x4 aO = {0,0,0,0}, g0 = {0,0,0,0}, g1 = {0,0,0,0};
            f32x4 g2i = {0,0,0,0}, g2h = {0,0,0,0};
#pragma unroll
            for (int k = 0; k < 5; ++k) {
                f16x8 af = *(const f16x8*)(Uf + ln * UST + k * 32 + lq * 8);
                aO = MFMA16(af, wD1r[k], aO);
                f16x8 b0 = *(const f16x8*)(GL + ((0 + tg) * 5 + k) * 512 + lane * 8);
                g0 = MFMA16(af, b0, g0);
                f16x8 b1 = *(const f16x8*)(GL + ((8 + tg) * 5 + k) * 512 + lane * 8);
                g1 = MFMA16(af, b1, g1);
                f16x8 b2 = *(const f16x8*)(GL + ((16 + tg) * 5 + k) * 512 + lane * 8);
                if (k == 0) g2i = MFMA16(af, b2, g2i);
                else        g2h = MFMA16(af, b2, g2h);
            }
            int c = tg * 16 + ln;
            float bD = bD1L[c];
            float br = bIHL[c] + bHHL[c];
            float bz = bIHL[128 + c] + bHHL[128 + c];
            float bgi = bIHL[256 + c], bgh = bHHL[256 + c];
#pragma unroll
            for (int j = 0; j < 4; ++j) {
                int row = lq * 4 + j;
                aAf[row * AST + c] = f2h(fmaxf(aO[j] + bD, 0.f));
                float rr = fsig_(g0[j] + br);
                float zz = fsig_(g1[j] + bz);
                float nn = ftanh_(fmaf(rr, g2h[j] + bgh, g2i[j] + bgi));
                float hold = h2f(Uf[row * UST + 32 + c]);
                hn[j] = fmaf(zz, hold - nn, nn);
            }
        }
        __syncthreads();

        // ---- P7: h write + dec2 (D2 streamed; all 8 waves active -> hidden) ----
        {
            f16x8 bd2[4];
#pragma unroll
            for (int k = 0; k < 4; ++k)
                bd2[k] = W8[OF_D2 / 8 + (tg * 4 + k) * 64 + lane];
            int c = tg * 16 + ln;
#pragma unroll
            for (int j = 0; j < 4; ++j)
                Uf[(lq * 4 + j) * UST + 32 + c] = f2h(hn[j]);
            f32x4 acc = {0,0,0,0};
#pragma unroll
            for (int k = 0; k < 4; ++k) {
                f16x8 af = *(const f16x8*)(aAf + ln * AST + k * 32 + lq * 8);
                acc = MFMA16(af, bd2[k], acc);
            }
            float bE = bD2L[c];
#pragma unroll
            for (int j = 0; j < 4; ++j)
                aBf[(lq * 4 + j) * AST + c] = f2h(fmaxf(acc[j] + bE, 0.f));
        }
        __syncthreads();
    }

    // ---- epilogue: dec-heads + NLL for step NS-1 ----
    if (wave == 0) {
        f32x4 acc = {0, 0, 0, 0};
#pragma unroll
        for (int k = 0; k < 4; ++k) {
            f16x8 af = *(const f16x8*)(aBf + ln * AST + k * 32 + lq * 8);
            f16x8 bf = W8[OF_DH / 8 + k * 64 + lane];
            acc = MFMA16(af, bf, acc);
        }
        if (ln < 4) {
            float bb = bDHl[ln];
#pragma unroll
            for (int j = 0; j < 4; ++j) {
                int row = lq * 4 + j;
                float v = acc[j] + bb;
                if (ln < 2) dmuL[row][ln] = v;
                else        dsdL[row][ln - 2] = fsoftplus_(v);
            }
        }
        asm volatile("s_waitcnt lgkmcnt(0)" ::: "memory");
        if (lane < 32) {
            int r = lane >> 1, xd = lane & 1;
            float d = xf2[(NS - 1) & 1][r][xd] - dmuL[r][xd];
            float isd = frcp_(dsdL[r][xd]);
            nll_acc += 0.5f * (d * d * isd * isd - 2.f * __logf(isd) + LOG2PI_F);
        }
    }

    // ---- block reduction ----
    __syncthreads();
    {
        float k = kl_acc, n = nll_acc;
        k += __shfl_xor(k, 1);  n += __shfl_xor(n, 1);
        k += __shfl_xor(k, 2);  n += __shfl_xor(n, 2);
        k += __shfl_xor(k, 4);  n += __shfl_xor(n, 4);
        k += __shfl_xor(k, 8);  n += __shfl_xor(n, 8);
        k += __shfl_xor(k, 16); n += __shfl_xor(n, 16);
        k += __shfl_xor(k, 32); n += __shfl_xor(n, 32);
        if (lane == 0) { redW[wave] = k; redW[16 + wave] = n; }
    }
    __syncthreads();
    if (tid == 0) {
        float s = 0.f, s2 = 0.f;
#pragma unroll
        for (int i = 0; i < 8; ++i) { s += redW[i]; s2 += redW[16 + i]; }
        p.partials[blockIdx.x] = s;
        p.partials[NWG + blockIdx.x] = s2;
    }
}

// ---------------- prep: pack weights into B-fragment order ----------------
struct PrepP {
    const float* eW1; const float* pW1; const float* dW1;
    const float* wih; const float* whh;
    const float* eW2; const float* pW2; const float* dW2;
    const float* hW[4];
    const float* dmW; const float* dsW;
    u16* dst;
};

__global__ void prep4(PrepP pp) {
    const int jNT[12]  = {8,8,8,24, 8,8,8, 1,1,1,1, 1};
    const int jKST[12] = {5,5,5,5, 4,4,4, 4,4,4,4, 4};
    const int jOFS[12] = {OF_E1,OF_P1,OF_D1,OF_G, OF_E2,OF_P2,OF_D2,
                          OF_H,OF_H+2048,OF_H+4096,OF_H+6144, OF_DH};
    const int jkt[3]   = {140,138,154};

    int job = blockIdx.y;
    int nt = jNT[job], kst = jKST[job];
    int per_agent = nt * kst * 512;
    int total = A_ * per_agent;
    int idx = blockIdx.x * 256 + threadIdx.x;
    if (idx >= total) return;
    int a = idx / per_agent;
    int rem = idx - a * per_agent;
    int slot = rem >> 9;            // /512
    int within = rem & 511;
    int lane = within >> 3, j = within & 7;
    int ntile = slot / kst, kstep = slot - ntile * kst;
    int k = kstep * 32 + (lane >> 4) * 8 + j;
    int n = ntile * 16 + (lane & 15);

    float val = 0.f;
    if (job < 3) {
        int sk = -1;
        if (job == 0)      sk = (k < 12) ? k : (k >= 32 ? k - 20 : -1);
        else if (job == 1) sk = (k >= 2 && k < 12) ? k - 2 : (k >= 32 ? k - 22 : -1);
        else               sk = (k >= 2 && k < 28) ? k - 2 : (k >= 32 ? k - 6 : -1);
        const float* s = (job == 0) ? pp.eW1 : (job == 1) ? pp.pW1 : pp.dW1;
        if (sk >= 0) val = s[((size_t)a * jkt[job] + sk) * 128 + n];
    } else if (job == 3) {
        if (k < 2)                  val = pp.wih[((size_t)a * 384 + n) * 18 + k];
        else if (k >= 12 && k < 28) val = pp.wih[((size_t)a * 384 + n) * 18 + (k - 10)];
        else if (k >= 32)           val = pp.whh[((size_t)a * 384 + n) * 128 + (k - 32)];
    } else if (job < 7) {
        const float* s = (job == 4) ? pp.eW2 : (job == 5) ? pp.pW2 : pp.dW2;
        val = s[((size_t)a * 128 + k) * 128 + n];
    } else if (job < 11) {
        val = pp.hW[job - 7][((size_t)a * 128 + k) * 16 + n];
    } else {
        if (n < 2)      val = pp.dmW[((size_t)a * 128 + k) * 2 + n];
        else if (n < 4) val = pp.dsW[((size_t)a * 128 + k) * 2 + (n - 2)];
    }
    pp.dst[(size_t)a * AGE + jOFS[job] + rem] = f2h(val);
}

__global__ void finish_kernel(const float* __restrict__ partials, float* __restrict__ out) {
    int tid = threadIdx.x;   // 64 threads
    float k = (tid < NWG) ? partials[tid] : 0.f;
    float n = (tid < NWG) ? partials[NWG + tid] : 0.f;
    k += __shfl_xor(k, 1);  n += __shfl_xor(n, 1);
    k += __shfl_xor(k, 2);  n += __shfl_xor(n, 2);
    k += __shfl_xor(k, 4);  n += __shfl_xor(n, 4);
    k += __shfl_xor(k, 8);  n += __shfl_xor(n, 8);
    k += __shfl_xor(k, 16); n += __shfl_xor(n, 16);
    k += __shfl_xor(k, 32); n += __shfl_xor(n, 32);
    if (tid == 0) { out[0] = k; out[1] = n; }
}

extern "C" void kernel_launch(void* const* d_in, const int* in_sizes, int n_in,
                              void* d_out, int out_size, void* d_ws, size_t ws_size,
                              hipStream_t stream) {
    float* partials = (float*)d_ws;                 // 80 floats
    u16* wq = (u16*)((char*)d_ws + 4096);           // packed frags, ~1.78 MB

    PrepP pp;
    pp.eW1 = (const float*)d_in[2];
    pp.pW1 = (const float*)d_in[10];
    pp.dW1 = (const float*)d_in[18];
    pp.wih = (const float*)d_in[26];
    pp.whh = (const float*)d_in[27];
    pp.eW2 = (const float*)d_in[4];
    pp.pW2 = (const float*)d_in[12];
    pp.dW2 = (const float*)d_in[20];
    pp.hW[0] = (const float*)d_in[6];   // emW
    pp.hW[1] = (const float*)d_in[8];   // esW
    pp.hW[2] = (const float*)d_in[14];  // pmW
    pp.hW[3] = (const float*)d_in[16];  // psW
    pp.dmW = (const float*)d_in[22];
    pp.dsW = (const float*)d_in[24];
    pp.dst = wq;
    prep4<<<dim3(1200, 12), 256, 0, stream>>>(pp);

    PM p;
    p.y   = (const float*)d_in[0];
    p.eps = (const float*)d_in[1];
    p.eb1 = (const float*)d_in[3];  p.eb2 = (const float*)d_in[5];
    p.emb = (const float*)d_in[7];  p.esb = (const float*)d_in[9];
    p.pb1 = (const float*)d_in[11]; p.pb2 = (const float*)d_in[13];
    p.pmb = (const float*)d_in[15]; p.psb = (const float*)d_in[17];
    p.db1 = (const float*)d_in[19]; p.db2 = (const float*)d_in[21];
    p.dmb = (const float*)d_in[23]; p.dsb = (const float*)d_in[25];
    p.bih = (const float*)d_in[28]; p.bhh = (const float*)d_in[29];
    p.wq = wq;
    p.partials = partials;

    vrnn15<<<NWG, NTH, 0, stream>>>(p);
    finish_kernel<<<1, 64, 0, stream>>>(partials, (float*)d_out);
}